// Round 1
// baseline (24845.781 us; speedup 1.0000x reference)
//
#include <hip/hip_runtime.h>
#include <cstdio>
#include <cstdint>

#define B_ 32
#define S_ 128
#define T_ 64
#define E_ 1024
#define H_ 1024
#define V_ 32000
#define G4_ 4096
#define K_ 1024

typedef _Float16 h8  __attribute__((ext_vector_type(8)));
typedef _Float16 h4v __attribute__((ext_vector_type(4)));
typedef float    f4  __attribute__((ext_vector_type(4)));

#define MFMA16(a,b,c) __builtin_amdgcn_mfma_f32_16x16x32_f16((a),(b),(c),0,0,0)

// Split fp32 -> (hi + lo/2048) fp16 pair, ~22-bit effective mantissa.
__device__ __forceinline__ void split8(const float* __restrict__ p, h8& hi, h8& lo) {
  f4 a = *(const f4*)p;
  f4 b = *(const f4*)(p + 4);
#pragma unroll
  for (int i = 0; i < 4; i++) {
    _Float16 h0 = (_Float16)a[i];
    hi[i] = h0;
    lo[i] = (_Float16)((a[i] - (float)h0) * 2048.0f);
    _Float16 h1 = (_Float16)b[i];
    hi[i + 4] = h1;
    lo[i + 4] = (_Float16)((b[i] - (float)h1) * 2048.0f);
  }
}

__device__ __forceinline__ float sigmoidf_(float x) { return 1.0f / (1.0f + expf(-x)); }

// ---------------- utility kernels ----------------

__global__ void k_zero_f32(float* __restrict__ p, int n) {
  int i = blockIdx.x * 256 + threadIdx.x;
  if (i < n) p[i] = 0.0f;
}

__global__ void k_zero_out0(float* __restrict__ out) {
  int i = blockIdx.x * 256 + threadIdx.x;
  if (i < B_ * V_) {
    int b = i / V_;
    int v = i - b * V_;
    out[(size_t)b * T_ * V_ + v] = 0.0f;
  }
}

// gather + split input embeddings: seq[n = s*32+b][k]
__global__ void k_embed(const int* __restrict__ toks, const float* __restrict__ emb,
                        _Float16* __restrict__ seqH, _Float16* __restrict__ seqL) {
  int n = blockIdx.x;          // n = t*32 + b
  int b = n & 31, t = n >> 5;
  int tok = toks[b * S_ + t];
  const float* src = emb + (size_t)tok * E_;
  int k = threadIdx.x * 4;
  f4 x = *(const f4*)(src + k);
  h4v hi, lo;
#pragma unroll
  for (int i = 0; i < 4; i++) {
    _Float16 h0 = (_Float16)x[i];
    hi[i] = h0;
    lo[i] = (_Float16)((x[i] - (float)h0) * 2048.0f);
  }
  *(h4v*)(seqH + (size_t)n * E_ + k) = hi;
  *(h4v*)(seqL + (size_t)n * E_ + k) = lo;
}

// pre-split the 6 recurrent weight matrices: [encWhh0,encWhh1,decWih0,decWih1,decWhh0,decWhh1]
__global__ void k_split_w(const float* __restrict__ encWhh, const float* __restrict__ decWih,
                          const float* __restrict__ decWhh,
                          _Float16* __restrict__ WH, _Float16* __restrict__ WL) {
  int blk = blockIdx.x;        // 0 .. 6*4096-1
  int mat = blk >> 12;
  int row = blk & 4095;
  const float* src;
  if (mat < 2)      src = encWhh + (size_t)mat * G4_ * K_;
  else if (mat < 4) src = decWih + (size_t)(mat - 2) * G4_ * K_;
  else              src = decWhh + (size_t)(mat - 4) * G4_ * K_;
  src += (size_t)row * K_;
  _Float16* dh = WH + (size_t)blk * K_;
  _Float16* dl = WL + (size_t)blk * K_;
  int k = threadIdx.x * 4;
  f4 x = *(const f4*)(src + k);
  h4v hi, lo;
#pragma unroll
  for (int i = 0; i < 4; i++) {
    _Float16 h0 = (_Float16)x[i];
    hi[i] = h0;
    lo[i] = (_Float16)((x[i] - (float)h0) * 2048.0f);
  }
  *(h4v*)(dh + k) = hi;
  *(h4v*)(dl + k) = lo;
}

// P[nn][j'] = seq[n] @ Wih^T + bih + bhh   for one 32-timestep chunk (nn = n - chunk*1024)
__global__ void k_precomp(const _Float16* __restrict__ seqH, const _Float16* __restrict__ seqL,
                          const float* __restrict__ Wih, const float* __restrict__ bih,
                          const float* __restrict__ bhh, float* __restrict__ P, int chunk) {
  int lane = threadIdx.x;       // 64
  int Wv = blockIdx.x;          // 2048 waves
  int mt = Wv & 63;             // 16-row tile within chunk
  int grp = Wv >> 6;            // 0..31, 8 j-tiles each
  int rowA = chunk * 1024 + mt * 16 + (lane & 15);
  const _Float16* aH = seqH + (size_t)rowA * K_;
  const _Float16* aL = seqL + (size_t)rowA * K_;
  int kof = (lane >> 4) * 8;
  int jbase = grp * 128 + (lane & 15);
  f4 accH[8] = {};
  f4 accM[8] = {};
  for (int ks = 0; ks < 32; ks++) {
    int k0 = ks * 32 + kof;
    h8 Ah = *(const h8*)(aH + k0);
    h8 Al = *(const h8*)(aL + k0);
#pragma unroll
    for (int jj = 0; jj < 8; jj++) {
      const float* wrow = Wih + (size_t)(jbase + jj * 16) * K_ + k0;
      h8 Bh, Bl;
      split8(wrow, Bh, Bl);
      accH[jj] = MFMA16(Ah, Bh, accH[jj]);
      accM[jj] = MFMA16(Ah, Bl, accM[jj]);
      accM[jj] = MFMA16(Al, Bh, accM[jj]);
    }
  }
  int nn = mt * 16 + (lane >> 4) * 4;
#pragma unroll
  for (int jj = 0; jj < 8; jj++) {
    int j = jbase + jj * 16;
    float bias = bih[j] + bhh[j];
#pragma unroll
    for (int r = 0; r < 4; r++) {
      P[(size_t)(nn + r) * G4_ + j] = accH[jj][r] + accM[jj][r] * (1.0f / 2048.0f) + bias;
    }
  }
}

// one encoder recurrent step: gates = P[t] + h @ Whh^T ; LSTM cell; h,c update (+ seq write for layer 0)
__global__ void k_enc_step(const _Float16* __restrict__ WH, const _Float16* __restrict__ WL,
                           const _Float16* __restrict__ hHin, const _Float16* __restrict__ hLin,
                           _Float16* __restrict__ hHout, _Float16* __restrict__ hLout,
                           float* __restrict__ cbuf, const float* __restrict__ P, int t_in_chunk,
                           _Float16* __restrict__ seqH, _Float16* __restrict__ seqL,
                           int t, int write_seq) {
  int lane = threadIdx.x;       // 64
  int Wv = blockIdx.x;          // 128 waves
  int mt = Wv & 1;
  int jt = Wv >> 1;
  int bA = mt * 16 + (lane & 15);
  const _Float16* aH = hHin + (size_t)bA * H_;
  const _Float16* aL = hLin + (size_t)bA * H_;
  int kof = (lane >> 4) * 8;
  int jcol = jt * 16 + (lane & 15);
  f4 accH[4] = {};
  f4 accM[4] = {};
  for (int ks = 0; ks < 32; ks++) {
    int k0 = ks * 32 + kof;
    h8 Ah = *(const h8*)(aH + k0);
    h8 Al = *(const h8*)(aL + k0);
#pragma unroll
    for (int g = 0; g < 4; g++) {
      h8 Bh = *(const h8*)(WH + (size_t)(g * H_ + jcol) * K_ + k0);
      h8 Bl = *(const h8*)(WL + (size_t)(g * H_ + jcol) * K_ + k0);
      accH[g] = MFMA16(Ah, Bh, accH[g]);
      accM[g] = MFMA16(Ah, Bl, accM[g]);
      accM[g] = MFMA16(Al, Bh, accM[g]);
    }
  }
  int b0 = mt * 16 + (lane >> 4) * 4;
#pragma unroll
  for (int r = 0; r < 4; r++) {
    int b = b0 + r;
    int prow = t_in_chunk * 32 + b;
    float gv[4];
#pragma unroll
    for (int g = 0; g < 4; g++)
      gv[g] = accH[g][r] + accM[g][r] * (1.0f / 2048.0f) + P[(size_t)prow * G4_ + g * H_ + jcol];
    float ii = sigmoidf_(gv[0]);
    float ff = sigmoidf_(gv[1]);
    float gt = tanhf(gv[2]);
    float oo = sigmoidf_(gv[3]);
    size_t ci = (size_t)b * H_ + jcol;
    float cn = ff * cbuf[ci] + ii * gt;
    cbuf[ci] = cn;
    float hn = oo * tanhf(cn);
    _Float16 hh = (_Float16)hn;
    _Float16 hl = (_Float16)((hn - (float)hh) * 2048.0f);
    hHout[ci] = hh;
    hLout[ci] = hl;
    if (write_seq) {
      size_t si = ((size_t)t * 32 + b) * E_ + jcol;
      seqH[si] = hh;
      seqL[si] = hl;
    }
  }
}

// one decoder LSTM cell. LAYER0: x = out_emb[tok] (inline split); else x = (xH,xL) = h0_new.
template <int LAYER0>
__global__ void k_dec_cell(const _Float16* __restrict__ WHi, const _Float16* __restrict__ WLi,
                           const _Float16* __restrict__ WHh, const _Float16* __restrict__ WLh,
                           const float* __restrict__ bih, const float* __restrict__ bhh,
                           const _Float16* __restrict__ hHin, const _Float16* __restrict__ hLin,
                           _Float16* __restrict__ hHout, _Float16* __restrict__ hLout,
                           float* __restrict__ cbuf,
                           const float* __restrict__ out_emb, const int* __restrict__ target,
                           const int* __restrict__ tf_mask, unsigned long long* __restrict__ amax,
                           const _Float16* __restrict__ xH, const _Float16* __restrict__ xL,
                           int step) {
  if (!LAYER0 && blockIdx.x == 0 && threadIdx.x < 32) amax[threadIdx.x] = 0ull;  // reset for this step's proj
  int lane = threadIdx.x;
  int Wv = blockIdx.x;
  int mt = Wv & 1;
  int jt = Wv >> 1;
  int bA = mt * 16 + (lane & 15);
  int kof = (lane >> 4) * 8;
  int jcol = jt * 16 + (lane & 15);
  f4 accH[4] = {};
  f4 accM[4] = {};

  const float* xrow = nullptr;
  const _Float16* axH = nullptr;
  const _Float16* axL = nullptr;
  if (LAYER0) {
    int tok;
    if (step == 0) tok = target[bA * T_];
    else if (tf_mask[step] > 0) tok = target[bA * T_ + step];
    else tok = (int)(~(unsigned)amax[bA]);
    xrow = out_emb + (size_t)tok * E_;
  } else {
    axH = xH + (size_t)bA * H_;
    axL = xL + (size_t)bA * H_;
  }

  // phase X: x @ Wih^T
  for (int ks = 0; ks < 32; ks++) {
    int k0 = ks * 32 + kof;
    h8 Ah, Al;
    if (LAYER0) {
      split8(xrow + k0, Ah, Al);
    } else {
      Ah = *(const h8*)(axH + k0);
      Al = *(const h8*)(axL + k0);
    }
#pragma unroll
    for (int g = 0; g < 4; g++) {
      h8 Bh = *(const h8*)(WHi + (size_t)(g * H_ + jcol) * K_ + k0);
      h8 Bl = *(const h8*)(WLi + (size_t)(g * H_ + jcol) * K_ + k0);
      accH[g] = MFMA16(Ah, Bh, accH[g]);
      accM[g] = MFMA16(Ah, Bl, accM[g]);
      accM[g] = MFMA16(Al, Bh, accM[g]);
    }
  }
  // phase H: h @ Whh^T
  const _Float16* ahH = hHin + (size_t)bA * H_;
  const _Float16* ahL = hLin + (size_t)bA * H_;
  for (int ks = 0; ks < 32; ks++) {
    int k0 = ks * 32 + kof;
    h8 Ah = *(const h8*)(ahH + k0);
    h8 Al = *(const h8*)(ahL + k0);
#pragma unroll
    for (int g = 0; g < 4; g++) {
      h8 Bh = *(const h8*)(WHh + (size_t)(g * H_ + jcol) * K_ + k0);
      h8 Bl = *(const h8*)(WLh + (size_t)(g * H_ + jcol) * K_ + k0);
      accH[g] = MFMA16(Ah, Bh, accH[g]);
      accM[g] = MFMA16(Ah, Bl, accM[g]);
      accM[g] = MFMA16(Al, Bh, accM[g]);
    }
  }

  float bsum[4];
#pragma unroll
  for (int g = 0; g < 4; g++) bsum[g] = bih[g * H_ + jcol] + bhh[g * H_ + jcol];
  int b0 = mt * 16 + (lane >> 4) * 4;
#pragma unroll
  for (int r = 0; r < 4; r++) {
    int b = b0 + r;
    float gv[4];
#pragma unroll
    for (int g = 0; g < 4; g++)
      gv[g] = accH[g][r] + accM[g][r] * (1.0f / 2048.0f) + bsum[g];
    float ii = sigmoidf_(gv[0]);
    float ff = sigmoidf_(gv[1]);
    float gt = tanhf(gv[2]);
    float oo = sigmoidf_(gv[3]);
    size_t ci = (size_t)b * H_ + jcol;
    float cn = ff * cbuf[ci] + ii * gt;
    cbuf[ci] = cn;
    float hn = oo * tanhf(cn);
    _Float16 hh = (_Float16)hn;
    hHout[ci] = hh;
    hLout[ci] = (_Float16)((hn - (float)hh) * 2048.0f);
  }
}

// vocab projection + output write + packed atomic argmax
__global__ void k_proj(const _Float16* __restrict__ hH, const _Float16* __restrict__ hL,
                       const float* __restrict__ Wout, const float* __restrict__ bout,
                       float* __restrict__ out, unsigned long long* __restrict__ amax, int step) {
  int lane = threadIdx.x;
  int Wv = blockIdx.x;          // 4000 waves
  int mt = Wv & 1;
  int vt = Wv >> 1;             // 0..1999
  int bA = mt * 16 + (lane & 15);
  const _Float16* aH = hH + (size_t)bA * H_;
  const _Float16* aL = hL + (size_t)bA * H_;
  int kof = (lane >> 4) * 8;
  int vcol = vt * 16 + (lane & 15);
  const float* wrow = Wout + (size_t)vcol * K_;
  f4 accH = {};
  f4 accM = {};
  for (int ks = 0; ks < 32; ks++) {
    int k0 = ks * 32 + kof;
    h8 Ah = *(const h8*)(aH + k0);
    h8 Al = *(const h8*)(aL + k0);
    h8 Bh, Bl;
    split8(wrow + k0, Bh, Bl);
    accH = MFMA16(Ah, Bh, accH);
    accM = MFMA16(Ah, Bl, accM);
    accM = MFMA16(Al, Bh, accM);
  }
  float bias = bout[vcol];
  int b0 = mt * 16 + (lane >> 4) * 4;
  float vals[4];
#pragma unroll
  for (int r = 0; r < 4; r++) {
    float v = accH[r] + accM[r] * (1.0f / 2048.0f) + bias;
    vals[r] = v;
    out[(size_t)(b0 + r) * T_ * V_ + (size_t)(step + 1) * V_ + vcol] = v;
  }
#pragma unroll
  for (int r = 0; r < 4; r++) {
    float v = vals[r];
    unsigned id = (unsigned)vcol;
#pragma unroll
    for (int off = 1; off < 16; off <<= 1) {
      float ov = __shfl_xor(v, off, 64);
      unsigned oi = __shfl_xor(id, off, 64);
      if (ov > v || (ov == v && oi < id)) { v = ov; id = oi; }
    }
    if ((lane & 15) == 0) {
      unsigned kb = __float_as_uint(v);
      kb = (kb & 0x80000000u) ? ~kb : (kb | 0x80000000u);
      unsigned long long key = ((unsigned long long)kb << 32) | (unsigned)(~id);
      atomicMax(&amax[b0 + r], key);
    }
  }
}

// ---------------- host ----------------

extern "C" void kernel_launch(void* const* d_in, const int* in_sizes, int n_in,
                              void* d_out, int out_size, void* d_ws, size_t ws_size,
                              hipStream_t stream) {
  const int*   input_tokens = (const int*)d_in[0];
  const int*   target  = (const int*)d_in[1];
  const int*   tf_mask = (const int*)d_in[2];
  const float* in_emb  = (const float*)d_in[3];
  const float* out_emb = (const float*)d_in[4];
  const float* enc_Wih = (const float*)d_in[5];
  const float* enc_Whh = (const float*)d_in[6];
  const float* enc_bih = (const float*)d_in[7];
  const float* enc_bhh = (const float*)d_in[8];
  const float* dec_Wih = (const float*)d_in[9];
  const float* dec_Whh = (const float*)d_in[10];
  const float* dec_bih = (const float*)d_in[11];
  const float* dec_bhh = (const float*)d_in[12];
  const float* W_out   = (const float*)d_in[13];
  const float* b_out   = (const float*)d_in[14];
  float* out = (float*)d_out;

  char* ws = (char*)d_ws;
  size_t off = 0;
  auto alloc = [&](size_t bytes) { void* p = ws + off; off += (bytes + 255) & ~(size_t)255; return p; };
  _Float16* WH   = (_Float16*)alloc((size_t)6 * G4_ * K_ * 2);
  _Float16* WL   = (_Float16*)alloc((size_t)6 * G4_ * K_ * 2);
  _Float16* seqH = (_Float16*)alloc((size_t)4096 * K_ * 2);
  _Float16* seqL = (_Float16*)alloc((size_t)4096 * K_ * 2);
  float*    P    = (float*)   alloc((size_t)1024 * G4_ * 4);
  _Float16* hH   = (_Float16*)alloc((size_t)4 * 32 * H_ * 2);   // [layer][parity]
  _Float16* hL   = (_Float16*)alloc((size_t)4 * 32 * H_ * 2);
  float*    cbuf = (float*)   alloc((size_t)2 * 32 * H_ * 4);
  unsigned long long* amax = (unsigned long long*)alloc(32 * 8);
  fprintf(stderr, "[voicemodel] ws need=%zu have=%zu out_size=%d\n", off, ws_size, out_size);

  k_zero_out0<<<(B_ * V_ + 255) / 256, 256, 0, stream>>>(out);
  k_embed<<<4096, 256, 0, stream>>>(input_tokens, in_emb, seqH, seqL);
  k_split_w<<<6 * 4096, 256, 0, stream>>>(enc_Whh, dec_Wih, dec_Whh, WH, WL);

  const int hwords = 32 * H_ / 2;   // f16 buffer size in u32 words
  for (int l = 0; l < 2; l++) {
    k_zero_f32<<<(hwords + 255) / 256, 256, 0, stream>>>((float*)(hH + (size_t)(l * 2) * 32 * H_), hwords);
    k_zero_f32<<<(hwords + 255) / 256, 256, 0, stream>>>((float*)(hL + (size_t)(l * 2) * 32 * H_), hwords);
    k_zero_f32<<<(32 * H_ + 255) / 256, 256, 0, stream>>>(cbuf + (size_t)l * 32 * H_, 32 * H_);
    const _Float16* eWH = WH + (size_t)l * G4_ * K_;
    const _Float16* eWL = WL + (size_t)l * G4_ * K_;
    for (int chunk = 0; chunk < 4; chunk++) {
      k_precomp<<<2048, 64, 0, stream>>>(seqH, seqL, enc_Wih + (size_t)l * G4_ * K_,
                                         enc_bih + l * G4_, enc_bhh + l * G4_, P, chunk);
      for (int tt = 0; tt < 32; tt++) {
        int t = chunk * 32 + tt;
        int par = t & 1;
        _Float16* hHin  = hH + (size_t)(l * 2 + par) * 32 * H_;
        _Float16* hLin  = hL + (size_t)(l * 2 + par) * 32 * H_;
        _Float16* hHout = hH + (size_t)(l * 2 + (par ^ 1)) * 32 * H_;
        _Float16* hLout = hL + (size_t)(l * 2 + (par ^ 1)) * 32 * H_;
        k_enc_step<<<128, 64, 0, stream>>>(eWH, eWL, hHin, hLin, hHout, hLout,
                                           cbuf + (size_t)l * 32 * H_, P, tt,
                                           seqH, seqL, t, l == 0 ? 1 : 0);
      }
    }
  }

  for (int i = 0; i < 63; i++) {
    int par = i & 1;
    _Float16* h0Hin  = hH + (size_t)(0 * 2 + par) * 32 * H_;
    _Float16* h0Lin  = hL + (size_t)(0 * 2 + par) * 32 * H_;
    _Float16* h0Hout = hH + (size_t)(0 * 2 + (par ^ 1)) * 32 * H_;
    _Float16* h0Lout = hL + (size_t)(0 * 2 + (par ^ 1)) * 32 * H_;
    _Float16* h1Hin  = hH + (size_t)(1 * 2 + par) * 32 * H_;
    _Float16* h1Lin  = hL + (size_t)(1 * 2 + par) * 32 * H_;
    _Float16* h1Hout = hH + (size_t)(1 * 2 + (par ^ 1)) * 32 * H_;
    _Float16* h1Lout = hL + (size_t)(1 * 2 + (par ^ 1)) * 32 * H_;

    k_dec_cell<1><<<128, 64, 0, stream>>>(
        WH + (size_t)2 * G4_ * K_, WL + (size_t)2 * G4_ * K_,   // dec_Wih l0
        WH + (size_t)4 * G4_ * K_, WL + (size_t)4 * G4_ * K_,   // dec_Whh l0
        dec_bih + 0 * G4_, dec_bhh + 0 * G4_,
        h0Hin, h0Lin, h0Hout, h0Lout, cbuf + (size_t)0 * 32 * H_,
        out_emb, target, tf_mask, amax, nullptr, nullptr, i);

    k_dec_cell<0><<<128, 64, 0, stream>>>(
        WH + (size_t)3 * G4_ * K_, WL + (size_t)3 * G4_ * K_,   // dec_Wih l1
        WH + (size_t)5 * G4_ * K_, WL + (size_t)5 * G4_ * K_,   // dec_Whh l1
        dec_bih + 1 * G4_, dec_bhh + 1 * G4_,
        h1Hin, h1Lin, h1Hout, h1Lout, cbuf + (size_t)1 * 32 * H_,
        out_emb, target, tf_mask, amax, h0Hout, h0Lout, i);

    k_proj<<<4000, 64, 0, stream>>>(h1Hout, h1Lout, W_out, b_out, out, amax, i);
  }
}